// Round 3
// baseline (2747.645 us; speedup 1.0000x reference)
//
#include <hip/hip_runtime.h>
#include <cstdint>
#include <cstddef>

#define NN 200000
#define NE 600000
#define NG 8192
#define C0 32
#define C1 128
#define C2 256
#define MLPH 256
#define NCLS 10

__device__ __forceinline__ void atomAddF(float* p, float v) { unsafeAtomicAdd(p, v); }

__device__ __forceinline__ float b2f(unsigned short u) {
  union { unsigned u; float f; } v; v.u = ((unsigned)u) << 16; return v.f;
}
__device__ __forceinline__ unsigned short f2b(float f) {
  union { float f; unsigned u; } v; v.f = f;
  unsigned r = (v.u + 0x7FFF + ((v.u >> 16) & 1)) >> 16;
  return (unsigned short)r;
}
__device__ __forceinline__ float4 ldf4(const float* p) { return *(const float4*)p; }
__device__ __forceinline__ float4 ldf4(const unsigned short* p) {
  ushort4 u = *(const ushort4*)p;
  return make_float4(b2f(u.x), b2f(u.y), b2f(u.z), b2f(u.w));
}
__device__ __forceinline__ void stf(float* p, float a, float b, float c, float d) {
  *(float4*)p = make_float4(a, b, c, d);
}
__device__ __forceinline__ void stf(unsigned short* p, float a, float b, float c, float d) {
  ushort4 u; u.x = f2b(a); u.y = f2b(b); u.z = f2b(c); u.w = f2b(d);
  *(ushort4*)p = u;
}

// ---------------- small utility kernels ----------------
__global__ __launch_bounds__(256) void k_fill(float* __restrict__ p, int n, float v) {
  int i = blockIdx.x * 256 + threadIdx.x;
  if (i < n) p[i] = v;
}

__global__ __launch_bounds__(256) void k_deg(const int* __restrict__ dst, const int* __restrict__ et,
                                             float* __restrict__ deg) {
  int e = blockIdx.x * 256 + threadIdx.x;
  if (e < NE) atomAddF(&deg[(size_t)et[e] * NN + dst[e]], 1.f);
}

__global__ __launch_bounds__(256) void k_dinv(float* __restrict__ deg) {
  int i = blockIdx.x * 256 + threadIdx.x;
  if (i < 3 * NN) { float d = deg[i]; deg[i] = d > 0.f ? 1.f / sqrtf(d) : 0.f; }
}

__global__ __launch_bounds__(256) void k_counts(const int* __restrict__ batch, float* __restrict__ counts) {
  int n = blockIdx.x * 256 + threadIdx.x;
  if (n < NN) atomAddF(&counts[batch[n]], 1.f);
}

// ---------------- edge gather-scatter in INPUT channel space ----------------
// aggX[et][dst-lo][c] += dinv_et[src] * fold(h[src][c])   for dst in [lo, lo+nloc)
template <int CIN, typename TIN>
__global__ __launch_bounds__(256) void k_scatter(const int* __restrict__ src, const int* __restrict__ dst,
                                                 const int* __restrict__ et, const float* __restrict__ dinv,
                                                 const TIN* __restrict__ h, const float* __restrict__ scin,
                                                 const float* __restrict__ shin, float* __restrict__ aggX,
                                                 int lo, int nloc) {
  constexpr int TPE = (CIN == 32) ? 32 : 64;
  constexpr int V = CIN / TPE;  // 1 or 2
  const int idx = blockIdx.x * 256 + threadIdx.x;
  const int e = idx / TPE;
  const int lane = idx % TPE;
  if (e >= NE) return;
  const int dl = dst[e] - lo;
  if ((unsigned)dl >= (unsigned)nloc) return;
  const int t = et[e];
  const int s = src[e];
  const float dv = dinv[(size_t)t * NN + s];
  if (dv == 0.f) return;  // norm = dv_src*dv_dst = 0 -> zero contribution
  const TIN* hp = h + (size_t)s * CIN + lane * V;
  float* ap = aggX + ((size_t)t * nloc + dl) * CIN + lane * V;
#pragma unroll
  for (int j = 0; j < V; j++) {
    float v = (float)0;
    if constexpr (sizeof(TIN) == 2) v = b2f(((const unsigned short*)hp)[j]);
    else v = ((const float*)hp)[j];
    const int c = lane * V + j;
    if (scin) v = fmaf(v, scin[c], shin[c]);
    atomAddF(ap + j, v * dv);
  }
}

// ---------------- fused finish: out_rows = relu(X'@Wid+bid) + sum_k relu((dinv_k*aggX_k)@Wc_k+bc_k)
// Accumulates BN stats (sum, sumsq per channel); optional pre-BN pooling; optional out write.
template <int CIN, int COUT, typename TIN, typename TOUT>
__global__ __launch_bounds__(256) void k_finish(
    const TIN* __restrict__ X, const float* __restrict__ scin, const float* __restrict__ shin,
    const float* __restrict__ aggX, const float* __restrict__ dinv, int lo, int nloc,
    const float* __restrict__ Wid, const float* __restrict__ bid,
    const float* __restrict__ Wc, const float* __restrict__ bc,
    TOUT* __restrict__ out, float* __restrict__ stats,
    float* __restrict__ pooled, const int* __restrict__ batch, int do_pool) {
  __shared__ float xs[CIN * 68];
  __shared__ float s1[64], s2[64];
  const int ln0 = blockIdx.x * 64;
  const int n0 = lo + ln0;
  const int c0 = blockIdx.y * 64;
  const int lane = threadIdx.x & 63;
  const int wv = threadIdx.x >> 6;
  const int tx = threadIdx.x & 15;
  const int ty = threadIdx.x >> 4;
  float oacc[4][4];
#pragma unroll
  for (int a = 0; a < 4; a++)
#pragma unroll
    for (int b = 0; b < 4; b++) oacc[a][b] = 0.f;

  for (int m = 0; m < 4; m++) {
    // ---- stage input tile (transposed, padded) ----
    if (m == 0) {
      const TIN* xr = X + (size_t)(n0 + lane) * CIN;
      for (int i4 = wv; i4 < CIN / 4; i4 += 4) {
        float4 v = ldf4(xr + i4 * 4);
        if (scin) {
          v.x = fmaf(v.x, scin[i4 * 4 + 0], shin[i4 * 4 + 0]);
          v.y = fmaf(v.y, scin[i4 * 4 + 1], shin[i4 * 4 + 1]);
          v.z = fmaf(v.z, scin[i4 * 4 + 2], shin[i4 * 4 + 2]);
          v.w = fmaf(v.w, scin[i4 * 4 + 3], shin[i4 * 4 + 3]);
        }
        xs[(i4 * 4 + 0) * 68 + lane] = v.x;
        xs[(i4 * 4 + 1) * 68 + lane] = v.y;
        xs[(i4 * 4 + 2) * 68 + lane] = v.z;
        xs[(i4 * 4 + 3) * 68 + lane] = v.w;
      }
    } else {
      const float* ar = aggX + ((size_t)(m - 1) * nloc + ln0 + lane) * CIN;
      const float dv = dinv[(size_t)(m - 1) * NN + n0 + lane];
      for (int i4 = wv; i4 < CIN / 4; i4 += 4) {
        float4 v = *(const float4*)(ar + i4 * 4);
        xs[(i4 * 4 + 0) * 68 + lane] = v.x * dv;
        xs[(i4 * 4 + 1) * 68 + lane] = v.y * dv;
        xs[(i4 * 4 + 2) * 68 + lane] = v.z * dv;
        xs[(i4 * 4 + 3) * 68 + lane] = v.w * dv;
      }
    }
    __syncthreads();
    // ---- 64x64 GEMM, 4x4 per thread ----
    const float* W = (m == 0) ? Wid : Wc + (size_t)(m - 1) * CIN * COUT;
    const float* bp = (m == 0) ? bid : bc + (size_t)(m - 1) * COUT;
    const float* wp = W + c0 + tx * 4;
    float4 a0 = {0, 0, 0, 0}, a1 = a0, a2 = a0, a3 = a0;
#pragma unroll 4
    for (int i = 0; i < CIN; i++) {
      float4 xa = *(const float4*)&xs[i * 68 + ty * 4];
      float4 wb = *(const float4*)(wp + (size_t)i * COUT);
      a0.x = fmaf(xa.x, wb.x, a0.x); a0.y = fmaf(xa.x, wb.y, a0.y);
      a0.z = fmaf(xa.x, wb.z, a0.z); a0.w = fmaf(xa.x, wb.w, a0.w);
      a1.x = fmaf(xa.y, wb.x, a1.x); a1.y = fmaf(xa.y, wb.y, a1.y);
      a1.z = fmaf(xa.y, wb.z, a1.z); a1.w = fmaf(xa.y, wb.w, a1.w);
      a2.x = fmaf(xa.z, wb.x, a2.x); a2.y = fmaf(xa.z, wb.y, a2.y);
      a2.z = fmaf(xa.z, wb.z, a2.z); a2.w = fmaf(xa.z, wb.w, a2.w);
      a3.x = fmaf(xa.w, wb.x, a3.x); a3.y = fmaf(xa.w, wb.y, a3.y);
      a3.z = fmaf(xa.w, wb.z, a3.z); a3.w = fmaf(xa.w, wb.w, a3.w);
    }
    const float4 bb = *(const float4*)(bp + c0 + tx * 4);
    oacc[0][0] += fmaxf(a0.x + bb.x, 0.f); oacc[0][1] += fmaxf(a0.y + bb.y, 0.f);
    oacc[0][2] += fmaxf(a0.z + bb.z, 0.f); oacc[0][3] += fmaxf(a0.w + bb.w, 0.f);
    oacc[1][0] += fmaxf(a1.x + bb.x, 0.f); oacc[1][1] += fmaxf(a1.y + bb.y, 0.f);
    oacc[1][2] += fmaxf(a1.z + bb.z, 0.f); oacc[1][3] += fmaxf(a1.w + bb.w, 0.f);
    oacc[2][0] += fmaxf(a2.x + bb.x, 0.f); oacc[2][1] += fmaxf(a2.y + bb.y, 0.f);
    oacc[2][2] += fmaxf(a2.z + bb.z, 0.f); oacc[2][3] += fmaxf(a2.w + bb.w, 0.f);
    oacc[3][0] += fmaxf(a3.x + bb.x, 0.f); oacc[3][1] += fmaxf(a3.y + bb.y, 0.f);
    oacc[3][2] += fmaxf(a3.z + bb.z, 0.f); oacc[3][3] += fmaxf(a3.w + bb.w, 0.f);
    __syncthreads();
  }

  // ---- epilogue: out write ----
  if (out) {
#pragma unroll
    for (int a = 0; a < 4; a++) {
      const int n = n0 + ty * 4 + a;
      stf(out + (size_t)n * COUT + c0 + tx * 4, oacc[a][0], oacc[a][1], oacc[a][2], oacc[a][3]);
    }
  }
  // ---- BN stats via LDS reduction ----
  if (threadIdx.x < 64) { s1[threadIdx.x] = 0.f; s2[threadIdx.x] = 0.f; }
  __syncthreads();
#pragma unroll
  for (int b = 0; b < 4; b++) {
    float p1 = 0.f, p2 = 0.f;
#pragma unroll
    for (int a = 0; a < 4; a++) { float v = oacc[a][b]; p1 += v; p2 += v * v; }
    atomicAdd(&s1[tx * 4 + b], p1);
    atomicAdd(&s2[tx * 4 + b], p2);
  }
  __syncthreads();
  if (threadIdx.x < 64) {
    atomAddF(&stats[c0 + threadIdx.x], s1[threadIdx.x]);
    atomAddF(&stats[COUT + c0 + threadIdx.x], s2[threadIdx.x]);
  }
  // ---- pre-BN pooling ----
  if (do_pool) {
#pragma unroll
    for (int a = 0; a < 4; a++) {
      const int n = n0 + ty * 4 + a;
      float* pp = pooled + (size_t)batch[n] * C2 + c0 + tx * 4;
      atomAddF(pp + 0, oacc[a][0]); atomAddF(pp + 1, oacc[a][1]);
      atomAddF(pp + 2, oacc[a][2]); atomAddF(pp + 3, oacc[a][3]);
    }
  }
}

// ---------------- BN finalize -> per-channel scale/shift ----------------
__global__ __launch_bounds__(256) void k_bnfin(const float* __restrict__ stats, const float* __restrict__ gamma,
                                               const float* __restrict__ beta, float* __restrict__ sc,
                                               float* __restrict__ sh, int COUT) {
  int c = threadIdx.x;
  if (c < COUT) {
    const float invN = 1.f / (float)NN;
    float m = stats[c] * invN;
    float v = stats[COUT + c] * invN - m * m;
    float s = gamma[c] / sqrtf(v + 1e-5f);
    sc[c] = s;
    sh[c] = fmaf(-m, s, beta[c]);
  }
}

// ---------------- MLP head: BN2 affine folded into pooled sums ----------------
__global__ __launch_bounds__(256) void k_mlp(const float* __restrict__ pooled, const float* __restrict__ counts,
                                             const float* __restrict__ sc2, const float* __restrict__ sh2,
                                             const float* __restrict__ Wf1, const float* __restrict__ bf1,
                                             const float* __restrict__ Wf2, const float* __restrict__ bf2,
                                             float* __restrict__ out) {
  __shared__ float feat[257];
  __shared__ float hid[256];
  const int g = blockIdx.x, t = threadIdx.x;
  const float cnt = counts[g];
  feat[t] = fmaf(sc2[t], pooled[(size_t)g * C2 + t], sh2[t] * cnt);
  if (t == 0) feat[256] = cnt * 0.025f;  // cnt / 40
  __syncthreads();
  float acc = bf1[t];
  for (int i = 0; i < 257; i++) acc = fmaf(feat[i], Wf1[(size_t)i * MLPH + t], acc);
  hid[t] = fmaxf(acc, 0.f);
  __syncthreads();
  if (t < NCLS) {
    float o = bf2[t];
    for (int j = 0; j < MLPH; j++) o = fmaf(hid[j], Wf2[(size_t)j * NCLS + t], o);
    out[(size_t)g * NCLS + t] = o;
  }
}

extern "C" void kernel_launch(void* const* d_in, const int* in_sizes, int n_in,
                              void* d_out, int out_size, void* d_ws, size_t ws_size,
                              hipStream_t stream) {
  const float* x = (const float*)d_in[0];
  const int* ei = (const int*)d_in[1];
  const int* et = (const int*)d_in[2];
  const int* batch = (const int*)d_in[3];
  const float* Wc0 = (const float*)d_in[4];
  const float* bc0 = (const float*)d_in[5];
  const float* Wid0 = (const float*)d_in[6];
  const float* bid0 = (const float*)d_in[7];
  const float* gm0 = (const float*)d_in[8];
  const float* bt0 = (const float*)d_in[9];
  const float* Wc1 = (const float*)d_in[10];
  const float* bc1 = (const float*)d_in[11];
  const float* Wid1 = (const float*)d_in[12];
  const float* bid1 = (const float*)d_in[13];
  const float* gm1 = (const float*)d_in[14];
  const float* bt1 = (const float*)d_in[15];
  const float* Wf1 = (const float*)d_in[16];
  const float* bf1 = (const float*)d_in[17];
  const float* Wf2 = (const float*)d_in[18];
  const float* bf2 = (const float*)d_in[19];
  const int* srcI = ei;
  const int* dstI = ei + NE;
  float* outp = (float*)d_out;

  char* ws = (char*)d_ws;
  size_t off = 0;
  auto take = [&](size_t bytes) -> char* {
    char* p = ws + off;
    off = (off + bytes + 255) & ~(size_t)255;
    return p;
  };
  float* dinv = (float*)take((size_t)3 * NN * 4);
  float* stats1 = (float*)take(2 * C1 * 4);
  float* stats2 = (float*)take(2 * C2 * 4);
  float* sc1 = (float*)take(C1 * 4);
  float* sh1 = (float*)take(C1 * 4);
  float* sc2 = (float*)take(C2 * 4);
  float* sh2 = (float*)take(C2 * 4);
  float* counts = (float*)take((size_t)NG * 4);
  float* pooled = (float*)take((size_t)NG * C2 * 4);
  const size_t fixed_end = off;

  // ---- adaptive tiering on workspace ----
  const size_t h1_f32 = (size_t)NN * C1 * 4;   // 102.4 MB
  const size_t h1_b16 = (size_t)NN * C1 * 2;   // 51.2 MB
  bool h1f32;
  if (ws_size >= fixed_end + h1_f32 + (32u << 20)) h1f32 = true;
  else if (ws_size >= fixed_end + h1_b16 + (1u << 20)) h1f32 = false;
  else {  // diagnostic beacon: distinguishable from zero-output
    k_fill<<<(out_size + 255) / 256, 256, 0, stream>>>(outp, out_size, 100.f);
    return;
  }
  void* out1 = (void*)take(h1f32 ? h1_f32 : h1_b16);
  const size_t left = ws_size - off;
  float* aggX = (float*)(ws + off);
  long long ch1 = (long long)(left / ((size_t)3 * C0 * 4)) & ~63LL;
  long long ch2 = (long long)(left / ((size_t)3 * C1 * 4)) & ~63LL;
  if (ch1 > NN) ch1 = NN;
  if (ch2 > NN) ch2 = NN;
  if (ch2 < 64) {  // cannot proceed at all
    k_fill<<<(out_size + 255) / 256, 256, 0, stream>>>(outp, out_size, 100.f);
    return;
  }

  dim3 blk(256);
  hipMemsetAsync(dinv, 0, (size_t)3 * NN * 4, stream);
  hipMemsetAsync(stats1, 0, 2 * C1 * 4, stream);
  hipMemsetAsync(stats2, 0, 2 * C2 * 4, stream);
  hipMemsetAsync(counts, 0, (size_t)NG * 4, stream);
  hipMemsetAsync(pooled, 0, (size_t)NG * C2 * 4, stream);

  k_deg<<<(NE + 255) / 256, blk, 0, stream>>>(dstI, et, dinv);
  k_dinv<<<(3 * NN + 255) / 256, blk, 0, stream>>>(dinv);
  k_counts<<<(NN + 255) / 256, blk, 0, stream>>>(batch, counts);

  // ---- layer 1: x (32ch) -> out1 pre-BN (128ch), stats1 ----
  for (long long lo = 0; lo < NN; lo += ch1) {
    const int nloc = (int)((NN - lo < ch1) ? (NN - lo) : ch1);
    hipMemsetAsync(aggX, 0, (size_t)3 * nloc * C0 * 4, stream);
    k_scatter<C0, float><<<(NE * 32) / 256, blk, 0, stream>>>(srcI, dstI, et, dinv, x, nullptr, nullptr,
                                                              aggX, (int)lo, nloc);
    if (h1f32)
      k_finish<C0, C1, float, float><<<dim3(nloc / 64, C1 / 64), blk, 0, stream>>>(
          x, nullptr, nullptr, aggX, dinv, (int)lo, nloc, Wid0, bid0, Wc0, bc0,
          (float*)out1, stats1, nullptr, nullptr, 0);
    else
      k_finish<C0, C1, float, unsigned short><<<dim3(nloc / 64, C1 / 64), blk, 0, stream>>>(
          x, nullptr, nullptr, aggX, dinv, (int)lo, nloc, Wid0, bid0, Wc0, bc0,
          (unsigned short*)out1, stats1, nullptr, nullptr, 0);
  }
  k_bnfin<<<1, blk, 0, stream>>>(stats1, gm0, bt0, sc1, sh1, C1);

  // ---- layer 2: out1 (BN1 folded on read) -> stats2 + pre-BN pooled; out2 never materialized ----
  for (long long lo = 0; lo < NN; lo += ch2) {
    const int nloc = (int)((NN - lo < ch2) ? (NN - lo) : ch2);
    hipMemsetAsync(aggX, 0, (size_t)3 * nloc * C1 * 4, stream);
    if (h1f32) {
      k_scatter<C1, float><<<(NE * 64) / 256, blk, 0, stream>>>(srcI, dstI, et, dinv, (const float*)out1,
                                                                sc1, sh1, aggX, (int)lo, nloc);
      k_finish<C1, C2, float, float><<<dim3(nloc / 64, C2 / 64), blk, 0, stream>>>(
          (const float*)out1, sc1, sh1, aggX, dinv, (int)lo, nloc, Wid1, bid1, Wc1, bc1,
          nullptr, stats2, pooled, batch, 1);
    } else {
      k_scatter<C1, unsigned short><<<(NE * 64) / 256, blk, 0, stream>>>(srcI, dstI, et, dinv,
                                                                         (const unsigned short*)out1,
                                                                         sc1, sh1, aggX, (int)lo, nloc);
      k_finish<C1, C2, unsigned short, float><<<dim3(nloc / 64, C2 / 64), blk, 0, stream>>>(
          (const unsigned short*)out1, sc1, sh1, aggX, dinv, (int)lo, nloc, Wid1, bid1, Wc1, bc1,
          nullptr, stats2, pooled, batch, 1);
    }
  }
  k_bnfin<<<1, blk, 0, stream>>>(stats2, gm1, bt1, sc2, sh2, C2);

  // ---- MLP head ----
  k_mlp<<<NG, blk, 0, stream>>>(pooled, counts, sc2, sh2, Wf1, bf1, Wf2, bf2, outp);
}

// Round 4
// 1800.771 us; speedup vs baseline: 1.5258x; 1.5258x over previous
//
#include <hip/hip_runtime.h>
#include <cstdint>
#include <cstddef>

#define NN 200000
#define NE 600000
#define NG 8192
#define C0 32
#define C1 128
#define C2 256
#define MLPH 256
#define NCLS 10

typedef __attribute__((ext_vector_type(8))) short short8b;  // 8 bf16 = 4 VGPR
typedef __attribute__((ext_vector_type(4))) float f32x4;

__device__ __forceinline__ void atomAddF(float* p, float v) { unsafeAtomicAdd(p, v); }

__device__ __forceinline__ float b2f(unsigned short u) {
  union { unsigned u; float f; } v; v.u = ((unsigned)u) << 16; return v.f;
}
__device__ __forceinline__ unsigned short f2b(float f) {  // RNE
  union { float f; unsigned u; } v; v.f = f;
  return (unsigned short)((v.u + 0x7FFF + ((v.u >> 16) & 1)) >> 16);
}

// ---------------- small utility kernels ----------------
__global__ __launch_bounds__(256) void k_fill(float* __restrict__ p, int n, float v) {
  int i = blockIdx.x * 256 + threadIdx.x;
  if (i < n) p[i] = v;
}

__global__ __launch_bounds__(256) void k_deg(const int* __restrict__ dst, const int* __restrict__ et,
                                             float* __restrict__ deg) {
  int e = blockIdx.x * 256 + threadIdx.x;
  if (e < NE) atomAddF(&deg[(size_t)et[e] * NN + dst[e]], 1.f);
}

__global__ __launch_bounds__(256) void k_dinv(float* __restrict__ deg) {
  int i = blockIdx.x * 256 + threadIdx.x;
  if (i < 3 * NN) { float d = deg[i]; deg[i] = d > 0.f ? 1.f / sqrtf(d) : 0.f; }
}

__global__ __launch_bounds__(256) void k_counts(const int* __restrict__ batch, float* __restrict__ counts) {
  int n = blockIdx.x * 256 + threadIdx.x;
  if (n < NN) atomAddF(&counts[batch[n]], 1.f);
}

// ---------------- weight prep: fragment-ordered bf16 ----------------
// Layout: [m:4][p:COUT/64][kk:CIN/32][ct:4][l:64][j:8] shorts.
// Element (m,p,kk,ct,l,j) = W_m[ ki ][ c ], ki = kk*32 + (l>>4)*4 + (j&3) + 16*(j>>2),
//                                      c  = p*64 + ct*16 + (l&15).  (m=0 -> Wid, else Wc[m-1])
__global__ __launch_bounds__(256) void k_prepw(const float* __restrict__ Wid, const float* __restrict__ Wc,
                                               unsigned short* __restrict__ Wtf, int CIN_, int COUT_) {
  int i = blockIdx.x * 256 + threadIdx.x;
  if (i >= 4 * CIN_ * COUT_) return;
  int j = i & 7, lq = (i >> 3) & 63, ct = (i >> 9) & 3;
  int rest = i >> 11;
  int KK = CIN_ / 32, NP = COUT_ / 64;
  int kk = rest % KK; rest /= KK;
  int p = rest % NP; int m = rest / NP;
  int ki = kk * 32 + (lq >> 4) * 4 + (j & 3) + 16 * (j >> 2);
  int c = p * 64 + ct * 16 + (lq & 15);
  float wv = (m == 0) ? Wid[(size_t)ki * COUT_ + c] : Wc[(size_t)((m - 1) * CIN_ + ki) * COUT_ + c];
  Wtf[i] = f2b(wv);
}

// ---------------- edge gather-scatter in INPUT channel space ----------------
template <int CIN, typename TIN>
__global__ __launch_bounds__(256) void k_scatter(const int* __restrict__ src, const int* __restrict__ dst,
                                                 const int* __restrict__ et, const float* __restrict__ dinv,
                                                 const TIN* __restrict__ h, float* __restrict__ aggX,
                                                 int lo, int nloc) {
  constexpr int TPE = (CIN == 32) ? 32 : 64;
  constexpr int V = CIN / TPE;
  const int idx = blockIdx.x * 256 + threadIdx.x;
  const int e = idx / TPE;
  const int lane = idx % TPE;
  if (e >= NE) return;
  const int dl = dst[e] - lo;
  if ((unsigned)dl >= (unsigned)nloc) return;
  const int t = et[e];
  const int s = src[e];
  const float dv = dinv[(size_t)t * NN + s];
  if (dv == 0.f) return;
  const TIN* hp = h + (size_t)s * CIN + lane * V;
  float* ap = aggX + ((size_t)t * nloc + dl) * CIN + lane * V;
#pragma unroll
  for (int j = 0; j < V; j++) {
    float v;
    if constexpr (sizeof(TIN) == 2) v = b2f(((const unsigned short*)hp)[j]);
    else v = ((const float*)hp)[j];
    atomAddF(ap + j, v * dv);
  }
}

// ---------------- fused finish via bf16 MFMA ----------------
// run = relu(X@Wid+bid) + sum_k relu((dinv_k*aggX_k)@Wc_k+bc_k) for a 64-node x 64-col tile.
// 4 waves; wave w: A rows w*16+(l&15); D rows w*16+(l>>4)*4+j, cols ct*16+(l&15).
template <int CIN, int COUT, bool INBF16, bool WRITEOUT, bool DOPOOL>
__global__ __launch_bounds__(256) void k_fin(
    const void* __restrict__ Xv, const float* __restrict__ aggX, const float* __restrict__ dinv,
    int lo, int nloc, const unsigned short* __restrict__ Wtf,
    const float* __restrict__ bid, const float* __restrict__ bc,
    unsigned short* __restrict__ outb, float* __restrict__ stats,
    float* __restrict__ pooled, const int* __restrict__ batch) {
  constexpr int NP = COUT / 64;
  __shared__ float s1[64], s2[64];
  const int p = blockIdx.x;
  const int ln0 = blockIdx.y * 64;
  const int n0 = lo + ln0;
  const int c0 = p * 64;
  const int tid = threadIdx.x, w = tid >> 6, l = tid & 63, lr = l & 15, q = l >> 4;
  const int rA = w * 16 + lr;
  const int nA = n0 + rA;

  f32x4 run[4];
#pragma unroll
  for (int ct = 0; ct < 4; ct++) run[ct] = (f32x4){0.f, 0.f, 0.f, 0.f};

#pragma unroll
  for (int m = 0; m < 4; m++) {
    f32x4 acc[4];
#pragma unroll
    for (int ct = 0; ct < 4; ct++) acc[ct] = (f32x4){0.f, 0.f, 0.f, 0.f};
    const float* arow = nullptr;
    float dv = 1.f;
    if (m > 0) {
      arow = aggX + ((size_t)(m - 1) * nloc + ln0 + rA) * CIN;
      dv = dinv[(size_t)(m - 1) * NN + nA];
    }
    const short8b* bfr = (const short8b*)(Wtf) + ((size_t)(m * NP + p) * (CIN / 32)) * 256;
#pragma unroll
    for (int kk = 0; kk < CIN; kk += 32) {
      union { ushort4 u4[2]; short8b v; } fa;
      if (m == 0 && INBF16) {
        const unsigned short* xr = (const unsigned short*)Xv + (size_t)nA * CIN;
        fa.u4[0] = *(const ushort4*)(xr + kk + q * 4);
        fa.u4[1] = *(const ushort4*)(xr + kk + 16 + q * 4);
      } else {
        const float* srcp = (m == 0) ? (const float*)Xv + (size_t)nA * CIN : arow;
        float4 v0 = *(const float4*)(srcp + kk + q * 4);
        float4 v1 = *(const float4*)(srcp + kk + 16 + q * 4);
        fa.u4[0] = make_ushort4(f2b(v0.x * dv), f2b(v0.y * dv), f2b(v0.z * dv), f2b(v0.w * dv));
        fa.u4[1] = make_ushort4(f2b(v1.x * dv), f2b(v1.y * dv), f2b(v1.z * dv), f2b(v1.w * dv));
      }
      const short8b* bk = bfr + (size_t)(kk >> 5) * 256;
#pragma unroll
      for (int ct = 0; ct < 4; ct++)
        acc[ct] = __builtin_amdgcn_mfma_f32_16x16x32_bf16(fa.v, bk[ct * 64 + l], acc[ct], 0, 0, 0);
    }
    const float* bp = (m == 0) ? bid : bc + (size_t)(m - 1) * COUT;
#pragma unroll
    for (int ct = 0; ct < 4; ct++) {
      float bb = bp[c0 + ct * 16 + lr];
#pragma unroll
      for (int j = 0; j < 4; j++) run[ct][j] += fmaxf(acc[ct][j] + bb, 0.f);
    }
  }

  if (WRITEOUT) {
#pragma unroll
    for (int j = 0; j < 4; j++) {
      unsigned short* orow = outb + (size_t)(n0 + w * 16 + q * 4 + j) * COUT + c0 + lr;
#pragma unroll
      for (int ct = 0; ct < 4; ct++) orow[ct * 16] = f2b(run[ct][j]);
    }
  }
  if (tid < 64) { s1[tid] = 0.f; s2[tid] = 0.f; }
  __syncthreads();
#pragma unroll
  for (int ct = 0; ct < 4; ct++) {
    float a1 = 0.f, a2 = 0.f;
#pragma unroll
    for (int j = 0; j < 4; j++) { float v = run[ct][j]; a1 += v; a2 += v * v; }
    atomicAdd(&s1[ct * 16 + lr], a1);
    atomicAdd(&s2[ct * 16 + lr], a2);
  }
  __syncthreads();
  if (tid < 64) {
    atomAddF(&stats[c0 + tid], s1[tid]);
    atomAddF(&stats[COUT + c0 + tid], s2[tid]);
  }
  if (DOPOOL) {
#pragma unroll
    for (int j = 0; j < 4; j++) {
      const int bn = batch[n0 + w * 16 + q * 4 + j];
      float* pp = pooled + (size_t)bn * C2 + c0;
#pragma unroll
      for (int ct = 0; ct < 4; ct++) atomAddF(pp + ct * 16 + lr, run[ct][j]);
    }
  }
}

// ---------------- BN finalize -> per-channel scale/shift ----------------
__global__ __launch_bounds__(256) void k_bnfin(const float* __restrict__ stats, const float* __restrict__ gamma,
                                               const float* __restrict__ beta, float* __restrict__ sc,
                                               float* __restrict__ sh, int COUT) {
  int c = threadIdx.x;
  if (c < COUT) {
    const float invN = 1.f / (float)NN;
    float m = stats[c] * invN;
    float v = stats[COUT + c] * invN - m * m;
    float s = gamma[c] / sqrtf(v + 1e-5f);
    sc[c] = s;
    sh[c] = fmaf(-m, s, beta[c]);
  }
}

// ---------------- fold BN1 into out1 (bf16, in place) ----------------
__global__ __launch_bounds__(256) void k_bnfold(unsigned short* __restrict__ o, const float* __restrict__ sc,
                                                const float* __restrict__ sh) {
  size_t i8 = ((size_t)blockIdx.x * 256 + threadIdx.x) * 8;
  if (i8 >= (size_t)NN * C1) return;
  const int c = (int)(i8 & (C1 - 1));
  ushort4 a = *(ushort4*)(o + i8);
  ushort4 b = *(ushort4*)(o + i8 + 4);
  a.x = f2b(fmaf(b2f(a.x), sc[c + 0], sh[c + 0]));
  a.y = f2b(fmaf(b2f(a.y), sc[c + 1], sh[c + 1]));
  a.z = f2b(fmaf(b2f(a.z), sc[c + 2], sh[c + 2]));
  a.w = f2b(fmaf(b2f(a.w), sc[c + 3], sh[c + 3]));
  b.x = f2b(fmaf(b2f(b.x), sc[c + 4], sh[c + 4]));
  b.y = f2b(fmaf(b2f(b.y), sc[c + 5], sh[c + 5]));
  b.z = f2b(fmaf(b2f(b.z), sc[c + 6], sh[c + 6]));
  b.w = f2b(fmaf(b2f(b.w), sc[c + 7], sh[c + 7]));
  *(ushort4*)(o + i8) = a;
  *(ushort4*)(o + i8 + 4) = b;
}

// ---------------- MLP head: BN2 affine folded into pooled sums ----------------
__global__ __launch_bounds__(256) void k_mlp(const float* __restrict__ pooled, const float* __restrict__ counts,
                                             const float* __restrict__ sc2, const float* __restrict__ sh2,
                                             const float* __restrict__ Wf1, const float* __restrict__ bf1,
                                             const float* __restrict__ Wf2, const float* __restrict__ bf2,
                                             float* __restrict__ out) {
  __shared__ float feat[257];
  __shared__ float hid[256];
  const int g = blockIdx.x, t = threadIdx.x;
  const float cnt = counts[g];
  feat[t] = fmaf(sc2[t], pooled[(size_t)g * C2 + t], sh2[t] * cnt);
  if (t == 0) feat[256] = cnt * 0.025f;
  __syncthreads();
  float acc = bf1[t];
  for (int i = 0; i < 257; i++) acc = fmaf(feat[i], Wf1[(size_t)i * MLPH + t], acc);
  hid[t] = fmaxf(acc, 0.f);
  __syncthreads();
  if (t < NCLS) {
    float o = bf2[t];
    for (int j = 0; j < MLPH; j++) o = fmaf(hid[j], Wf2[(size_t)j * NCLS + t], o);
    out[(size_t)g * NCLS + t] = o;
  }
}

extern "C" void kernel_launch(void* const* d_in, const int* in_sizes, int n_in,
                              void* d_out, int out_size, void* d_ws, size_t ws_size,
                              hipStream_t stream) {
  const float* x = (const float*)d_in[0];
  const int* ei = (const int*)d_in[1];
  const int* et = (const int*)d_in[2];
  const int* batch = (const int*)d_in[3];
  const float* Wc0 = (const float*)d_in[4];
  const float* bc0 = (const float*)d_in[5];
  const float* Wid0 = (const float*)d_in[6];
  const float* bid0 = (const float*)d_in[7];
  const float* gm0 = (const float*)d_in[8];
  const float* bt0 = (const float*)d_in[9];
  const float* Wc1 = (const float*)d_in[10];
  const float* bc1 = (const float*)d_in[11];
  const float* Wid1 = (const float*)d_in[12];
  const float* bid1 = (const float*)d_in[13];
  const float* gm1 = (const float*)d_in[14];
  const float* bt1 = (const float*)d_in[15];
  const float* Wf1 = (const float*)d_in[16];
  const float* bf1 = (const float*)d_in[17];
  const float* Wf2 = (const float*)d_in[18];
  const float* bf2 = (const float*)d_in[19];
  const int* srcI = ei;
  const int* dstI = ei + NE;
  float* outp = (float*)d_out;

  char* ws = (char*)d_ws;
  size_t off = 0;
  auto take = [&](size_t bytes) -> char* {
    char* p = ws + off;
    off = (off + bytes + 255) & ~(size_t)255;
    return p;
  };
  float* dinv = (float*)take((size_t)3 * NN * 4);
  float* stats1 = (float*)take(2 * C1 * 4);
  float* stats2 = (float*)take(2 * C2 * 4);
  float* sc1 = (float*)take(C1 * 4);
  float* sh1 = (float*)take(C1 * 4);
  float* sc2 = (float*)take(C2 * 4);
  float* sh2 = (float*)take(C2 * 4);
  float* counts = (float*)take((size_t)NG * 4);
  float* pooled = (float*)take((size_t)NG * C2 * 4);
  unsigned short* Wtf1 = (unsigned short*)take((size_t)4 * C0 * C1 * 2);
  unsigned short* Wtf2 = (unsigned short*)take((size_t)4 * C1 * C2 * 2);
  unsigned short* out1 = (unsigned short*)take((size_t)NN * C1 * 2);
  const size_t min_agg = (size_t)3 * 64 * C1 * 4;
  if (off + min_agg > ws_size) {
    k_fill<<<(out_size + 255) / 256, 256, 0, stream>>>(outp, out_size, 100.f);
    return;
  }
  float* aggX = (float*)(ws + off);
  const size_t left = ws_size - off;
  long long ch1 = (long long)(left / ((size_t)3 * C0 * 4)) & ~63LL;
  long long ch2 = (long long)(left / ((size_t)3 * C1 * 4)) & ~63LL;
  if (ch1 > NN) ch1 = NN;
  if (ch2 > NN) ch2 = NN;

  dim3 blk(256);
  hipMemsetAsync(dinv, 0, (size_t)3 * NN * 4, stream);
  hipMemsetAsync(stats1, 0, 2 * C1 * 4, stream);
  hipMemsetAsync(stats2, 0, 2 * C2 * 4, stream);
  hipMemsetAsync(counts, 0, (size_t)NG * 4, stream);
  hipMemsetAsync(pooled, 0, (size_t)NG * C2 * 4, stream);

  k_prepw<<<(4 * C0 * C1 + 255) / 256, blk, 0, stream>>>(Wid0, Wc0, Wtf1, C0, C1);
  k_prepw<<<(4 * C1 * C2 + 255) / 256, blk, 0, stream>>>(Wid1, Wc1, Wtf2, C1, C2);
  k_deg<<<(NE + 255) / 256, blk, 0, stream>>>(dstI, et, dinv);
  k_dinv<<<(3 * NN + 255) / 256, blk, 0, stream>>>(dinv);
  k_counts<<<(NN + 255) / 256, blk, 0, stream>>>(batch, counts);

  // ---- layer 1: x (f32, 32ch) -> out1 bf16 pre-BN (128ch) + stats1 ----
  for (long long lo = 0; lo < NN; lo += ch1) {
    const int nloc = (int)((NN - lo < ch1) ? (NN - lo) : ch1);
    hipMemsetAsync(aggX, 0, (size_t)3 * nloc * C0 * 4, stream);
    k_scatter<C0, float><<<(NE * 32) / 256, blk, 0, stream>>>(srcI, dstI, et, dinv, x, aggX, (int)lo, nloc);
    k_fin<C0, C1, false, true, false><<<dim3(C1 / 64, nloc / 64), blk, 0, stream>>>(
        x, aggX, dinv, (int)lo, nloc, Wtf1, bid0, bc0, out1, stats1, nullptr, nullptr);
  }
  k_bnfin<<<1, blk, 0, stream>>>(stats1, gm0, bt0, sc1, sh1, C1);
  k_bnfold<<<(int)(((size_t)NN * C1 / 8 + 255) / 256), blk, 0, stream>>>(out1, sc1, sh1);

  // ---- layer 2: out1 bf16 (BN1 folded) -> stats2 + pre-BN pooled ----
  for (long long lo = 0; lo < NN; lo += ch2) {
    const int nloc = (int)((NN - lo < ch2) ? (NN - lo) : ch2);
    hipMemsetAsync(aggX, 0, (size_t)3 * nloc * C1 * 4, stream);
    k_scatter<C1, unsigned short><<<(NE * 64) / 256, blk, 0, stream>>>(srcI, dstI, et, dinv, out1, aggX,
                                                                       (int)lo, nloc);
    k_fin<C1, C2, true, false, true><<<dim3(C2 / 64, nloc / 64), blk, 0, stream>>>(
        out1, aggX, dinv, (int)lo, nloc, Wtf2, bid1, bc1, nullptr, stats2, pooled, batch);
  }
  k_bnfin<<<1, blk, 0, stream>>>(stats2, gm1, bt1, sc2, sh2, C2);

  // ---- MLP head ----
  k_mlp<<<NG, blk, 0, stream>>>(pooled, counts, sc2, sh2, Wf1, bf1, Wf2, bf2, outp);
}

// Round 5
// 870.063 us; speedup vs baseline: 3.1580x; 2.0697x over previous
//
#include <hip/hip_runtime.h>
#include <cstdint>
#include <cstddef>

#define NN 200000
#define NE 600000
#define NG 8192
#define C0 32
#define C1 128
#define C2 256
#define MLPH 256
#define NCLS 10
#define NB (3 * NN)
#define SCAN_BPB 1024
#define SCAN_NBLK ((NB + SCAN_BPB - 1) / SCAN_BPB)

typedef __attribute__((ext_vector_type(8))) short short8b;  // 8 bf16 = 4 VGPR
typedef __attribute__((ext_vector_type(4))) float f32x4;

__device__ __forceinline__ void atomAddF(float* p, float v) { unsafeAtomicAdd(p, v); }

__device__ __forceinline__ float b2f(unsigned short u) {
  union { unsigned u; float f; } v; v.u = ((unsigned)u) << 16; return v.f;
}
__device__ __forceinline__ unsigned short f2b(float f) {  // RNE
  union { float f; unsigned u; } v; v.f = f;
  return (unsigned short)((v.u + 0x7FFF + ((v.u >> 16) & 1)) >> 16);
}

// ---------------- small utility kernels ----------------
__global__ __launch_bounds__(256) void k_fill(float* __restrict__ p, int n, float v) {
  int i = blockIdx.x * 256 + threadIdx.x;
  if (i < n) p[i] = v;
}

__global__ __launch_bounds__(256) void k_counts(const int* __restrict__ batch, float* __restrict__ counts) {
  int n = blockIdx.x * 256 + threadIdx.x;
  if (n < NN) atomAddF(&counts[batch[n]], 1.f);
}

// ---------------- CSR build: histogram (= degree), scan, place ----------------
__global__ __launch_bounds__(256) void k_hist(const int* __restrict__ dst, const int* __restrict__ et,
                                              int* __restrict__ cnt) {
  int e = blockIdx.x * 256 + threadIdx.x;
  if (e < NE) atomicAdd(&cnt[et[e] * NN + dst[e]], 1);
}

__global__ __launch_bounds__(256) void k_dinvI(const int* __restrict__ cnt, float* __restrict__ dinv) {
  int i = blockIdx.x * 256 + threadIdx.x;
  if (i < NB) { int c = cnt[i]; dinv[i] = (c > 0) ? 1.f / sqrtf((float)c) : 0.f; }
}

__global__ __launch_bounds__(256) void k_scan1(const int* __restrict__ cnt, int* __restrict__ starts,
                                               int* __restrict__ bsum) {
  __shared__ int sh[256];
  const int b0 = blockIdx.x * SCAN_BPB + threadIdx.x * 4;
  int v[4]; int tot = 0;
#pragma unroll
  for (int j = 0; j < 4; j++) {
    int b = b0 + j;
    v[j] = tot;
    tot += (b < NB) ? cnt[b] : 0;
  }
  sh[threadIdx.x] = tot;
  __syncthreads();
  for (int ofs = 1; ofs < 256; ofs <<= 1) {
    int add = (threadIdx.x >= ofs) ? sh[threadIdx.x - ofs] : 0;
    __syncthreads();
    sh[threadIdx.x] += add;
    __syncthreads();
  }
  const int excl = (threadIdx.x == 0) ? 0 : sh[threadIdx.x - 1];
#pragma unroll
  for (int j = 0; j < 4; j++) {
    int b = b0 + j;
    if (b < NB) starts[b] = excl + v[j];
  }
  if (threadIdx.x == 255) bsum[blockIdx.x] = sh[255];
}

__global__ void k_scan2(int* __restrict__ bsum) {
  if (threadIdx.x == 0) {
    int acc = 0;
    for (int i = 0; i < SCAN_NBLK; i++) { int t = bsum[i]; bsum[i] = acc; acc += t; }
  }
}

__global__ __launch_bounds__(256) void k_scan3(int* __restrict__ starts, const int* __restrict__ bsum) {
  int b = blockIdx.x * 256 + threadIdx.x;
  if (b < NB) starts[b] += bsum[b / SCAN_BPB];
}

// After k_place, starts[b] == end(b); list for bin b = [b ? starts[b-1] : 0, starts[b])
__global__ __launch_bounds__(256) void k_place(const int* __restrict__ src, const int* __restrict__ dst,
                                               const int* __restrict__ et, int* __restrict__ starts,
                                               int* __restrict__ esrc) {
  int e = blockIdx.x * 256 + threadIdx.x;
  if (e >= NE) return;
  int b = et[e] * NN + dst[e];
  int pos = atomicAdd(&starts[b], 1);
  esrc[pos] = src[e];
}

// ---------------- weight prep: fragment-ordered bf16 ----------------
// [m:4][p:COUT/64][kk:CIN/32][ct:4][l:64][j:8]; ki = kk*32+(l>>4)*4+(j&3)+16*(j>>2), c = p*64+ct*16+(l&15)
__global__ __launch_bounds__(256) void k_prepw(const float* __restrict__ Wid, const float* __restrict__ Wc,
                                               unsigned short* __restrict__ Wtf, int CIN_, int COUT_) {
  int i = blockIdx.x * 256 + threadIdx.x;
  if (i >= 4 * CIN_ * COUT_) return;
  int j = i & 7, lq = (i >> 3) & 63, ct = (i >> 9) & 3;
  int rest = i >> 11;
  int KK = CIN_ / 32, NP = COUT_ / 64;
  int kk = rest % KK; rest /= KK;
  int p = rest % NP; int m = rest / NP;
  int ki = kk * 32 + (lq >> 4) * 4 + (j & 3) + 16 * (j >> 2);
  int c = p * 64 + ct * 16 + (lq & 15);
  float wv = (m == 0) ? Wid[(size_t)ki * COUT_ + c] : Wc[(size_t)((m - 1) * CIN_ + ki) * COUT_ + c];
  Wtf[i] = f2b(wv);
}

// ---------------- gather-reduce aggregation (CSR) ----------------
// aggXb[t*nloc+nl][c] = bf16( dinv_dst * sum_{e in list(t, lo+nl)} dinv_src * h[src][c] )
template <int CIN, typename TIN>
__global__ __launch_bounds__(256) void k_agg(const int* __restrict__ starts, const int* __restrict__ esrc,
                                             const float* __restrict__ dinv, const TIN* __restrict__ h,
                                             unsigned short* __restrict__ aggXb, int lo, int nloc) {
  constexpr int TPB = (CIN == 32) ? 32 : 64;
  constexpr int V = CIN / TPB;  // 1 or 2
  const int idx = blockIdx.x * 256 + threadIdx.x;
  const int bl = idx / TPB;
  const int lane = idx % TPB;
  if (bl >= 3 * nloc) return;
  const int t = bl / nloc;
  const int bin = t * NN + lo + (bl - t * nloc);
  const int s = (bin == 0) ? 0 : starts[bin - 1];
  const int e2 = starts[bin];
  float acc[V];
#pragma unroll
  for (int j = 0; j < V; j++) acc[j] = 0.f;
  for (int i = s; i < e2; i++) {
    const int sn = esrc[i];
    const float dv = dinv[(size_t)t * NN + sn];
    if (dv == 0.f) continue;
    const TIN* hp = h + (size_t)sn * CIN + lane * V;
#pragma unroll
    for (int j = 0; j < V; j++) {
      float v;
      if constexpr (sizeof(TIN) == 2) v = b2f(((const unsigned short*)hp)[j]);
      else v = ((const float*)hp)[j];
      acc[j] = fmaf(v, dv, acc[j]);
    }
  }
  const float dvd = dinv[bin];
  unsigned short* op = aggXb + (size_t)bl * CIN + lane * V;
#pragma unroll
  for (int j = 0; j < V; j++) op[j] = f2b(acc[j] * dvd);
}

// ---------------- fused finish via bf16 MFMA ----------------
// run = relu(X@Wid+bid) + sum_k relu(aggXb_k@Wc_k+bc_k); LDS-tile epilogue for out/stats/pool.
template <int CIN, int COUT, bool INBF16, bool WRITEOUT, bool DOPOOL>
__global__ __launch_bounds__(256) void k_fin(
    const void* __restrict__ Xv, const unsigned short* __restrict__ aggXb,
    int lo, int nloc, const unsigned short* __restrict__ Wtf,
    const float* __restrict__ bid, const float* __restrict__ bc,
    unsigned short* __restrict__ outb, float* __restrict__ stats,
    float* __restrict__ pooled, const int* __restrict__ batch) {
  constexpr int NP = COUT / 64;
  __shared__ float tile[64][65];
  __shared__ int sbatch[64];
  const int p = blockIdx.x;
  const int ln0 = blockIdx.y * 64;
  const int n0 = lo + ln0;
  const int c0 = p * 64;
  const int tid = threadIdx.x, w = tid >> 6, l = tid & 63, lr = l & 15, q = l >> 4;
  const int rA = w * 16 + lr;
  const int nA = n0 + rA;

  f32x4 run[4];
#pragma unroll
  for (int ct = 0; ct < 4; ct++) run[ct] = (f32x4){0.f, 0.f, 0.f, 0.f};

#pragma unroll
  for (int m = 0; m < 4; m++) {
    f32x4 acc[4];
#pragma unroll
    for (int ct = 0; ct < 4; ct++) acc[ct] = (f32x4){0.f, 0.f, 0.f, 0.f};
    const unsigned short* ar = (m > 0) ? aggXb + ((size_t)(m - 1) * nloc + ln0 + rA) * CIN : nullptr;
    const short8b* bfr = (const short8b*)(Wtf) + ((size_t)(m * NP + p) * (CIN / 32)) * 256;
#pragma unroll
    for (int kk = 0; kk < CIN; kk += 32) {
      union { ushort4 u4[2]; short8b v; } fa;
      if (m > 0) {
        fa.u4[0] = *(const ushort4*)(ar + kk + q * 4);
        fa.u4[1] = *(const ushort4*)(ar + kk + 16 + q * 4);
      } else if (INBF16) {
        const unsigned short* xr = (const unsigned short*)Xv + (size_t)nA * CIN;
        fa.u4[0] = *(const ushort4*)(xr + kk + q * 4);
        fa.u4[1] = *(const ushort4*)(xr + kk + 16 + q * 4);
      } else {
        const float* xr = (const float*)Xv + (size_t)nA * CIN;
        float4 v0 = *(const float4*)(xr + kk + q * 4);
        float4 v1 = *(const float4*)(xr + kk + 16 + q * 4);
        fa.u4[0] = make_ushort4(f2b(v0.x), f2b(v0.y), f2b(v0.z), f2b(v0.w));
        fa.u4[1] = make_ushort4(f2b(v1.x), f2b(v1.y), f2b(v1.z), f2b(v1.w));
      }
      const short8b* bk = bfr + (size_t)(kk >> 5) * 256;
#pragma unroll
      for (int ct = 0; ct < 4; ct++)
        acc[ct] = __builtin_amdgcn_mfma_f32_16x16x32_bf16(fa.v, bk[ct * 64 + l], acc[ct], 0, 0, 0);
    }
    const float* bp = (m == 0) ? bid : bc + (size_t)(m - 1) * COUT;
#pragma unroll
    for (int ct = 0; ct < 4; ct++) {
      float bb = bp[c0 + ct * 16 + lr];
#pragma unroll
      for (int j = 0; j < 4; j++) run[ct][j] += fmaxf(acc[ct][j] + bb, 0.f);
    }
  }

  // ---- stage tile in LDS: row = node, col = channel ----
#pragma unroll
  for (int ct = 0; ct < 4; ct++)
#pragma unroll
    for (int j = 0; j < 4; j++) tile[w * 16 + q * 4 + j][ct * 16 + lr] = run[ct][j];
  if (DOPOOL && tid < 64) sbatch[tid] = batch[n0 + tid];
  __syncthreads();

  if (WRITEOUT) {
    const int r = tid >> 2, cg = (tid & 3) * 16;
    ushort4 o[4];
#pragma unroll
    for (int g4 = 0; g4 < 4; g4++) {
      o[g4].x = f2b(tile[r][cg + g4 * 4 + 0]);
      o[g4].y = f2b(tile[r][cg + g4 * 4 + 1]);
      o[g4].z = f2b(tile[r][cg + g4 * 4 + 2]);
      o[g4].w = f2b(tile[r][cg + g4 * 4 + 3]);
    }
    ushort4* dst4 = (ushort4*)(outb + (size_t)(n0 + r) * COUT + c0 + cg);
#pragma unroll
    for (int g4 = 0; g4 < 4; g4++) dst4[g4] = o[g4];
  }
  if (tid < 64) {
    float s = 0.f, ss = 0.f, gs = 0.f;
    int curg = DOPOOL ? sbatch[0] : 0;
    for (int r = 0; r < 64; r++) {
      float v = tile[r][tid];
      s += v; ss += v * v;
      if (DOPOOL) {
        int g = sbatch[r];
        if (g != curg) { atomAddF(&pooled[(size_t)curg * C2 + c0 + tid], gs); gs = 0.f; curg = g; }
        gs += v;
      }
    }
    if (DOPOOL) atomAddF(&pooled[(size_t)curg * C2 + c0 + tid], gs);
    atomAddF(&stats[c0 + tid], s);
    atomAddF(&stats[COUT + c0 + tid], ss);
  }
}

// ---------------- BN finalize -> per-channel scale/shift ----------------
__global__ __launch_bounds__(256) void k_bnfin(const float* __restrict__ stats, const float* __restrict__ gamma,
                                               const float* __restrict__ beta, float* __restrict__ sc,
                                               float* __restrict__ sh, int COUT) {
  int c = threadIdx.x;
  if (c < COUT) {
    const float invN = 1.f / (float)NN;
    float m = stats[c] * invN;
    float v = stats[COUT + c] * invN - m * m;
    float s = gamma[c] / sqrtf(v + 1e-5f);
    sc[c] = s;
    sh[c] = fmaf(-m, s, beta[c]);
  }
}

// ---------------- fold BN1 into out1 (bf16, in place) ----------------
__global__ __launch_bounds__(256) void k_bnfold(unsigned short* __restrict__ o, const float* __restrict__ sc,
                                                const float* __restrict__ sh) {
  size_t i8 = ((size_t)blockIdx.x * 256 + threadIdx.x) * 8;
  if (i8 >= (size_t)NN * C1) return;
  const int c = (int)(i8 & (C1 - 1));
  ushort4 a = *(ushort4*)(o + i8);
  ushort4 b = *(ushort4*)(o + i8 + 4);
  a.x = f2b(fmaf(b2f(a.x), sc[c + 0], sh[c + 0]));
  a.y = f2b(fmaf(b2f(a.y), sc[c + 1], sh[c + 1]));
  a.z = f2b(fmaf(b2f(a.z), sc[c + 2], sh[c + 2]));
  a.w = f2b(fmaf(b2f(a.w), sc[c + 3], sh[c + 3]));
  b.x = f2b(fmaf(b2f(b.x), sc[c + 4], sh[c + 4]));
  b.y = f2b(fmaf(b2f(b.y), sc[c + 5], sh[c + 5]));
  b.z = f2b(fmaf(b2f(b.z), sc[c + 6], sh[c + 6]));
  b.w = f2b(fmaf(b2f(b.w), sc[c + 7], sh[c + 7]));
  *(ushort4*)(o + i8) = a;
  *(ushort4*)(o + i8 + 4) = b;
}

// ---------------- MLP head: BN2 affine folded into pooled sums ----------------
__global__ __launch_bounds__(256) void k_mlp(const float* __restrict__ pooled, const float* __restrict__ counts,
                                             const float* __restrict__ sc2, const float* __restrict__ sh2,
                                             const float* __restrict__ Wf1, const float* __restrict__ bf1,
                                             const float* __restrict__ Wf2, const float* __restrict__ bf2,
                                             float* __restrict__ out) {
  __shared__ float feat[257];
  __shared__ float hid[256];
  const int g = blockIdx.x, t = threadIdx.x;
  const float cnt = counts[g];
  feat[t] = fmaf(sc2[t], pooled[(size_t)g * C2 + t], sh2[t] * cnt);
  if (t == 0) feat[256] = cnt * 0.025f;
  __syncthreads();
  float acc = bf1[t];
  for (int i = 0; i < 257; i++) acc = fmaf(feat[i], Wf1[(size_t)i * MLPH + t], acc);
  hid[t] = fmaxf(acc, 0.f);
  __syncthreads();
  if (t < NCLS) {
    float o = bf2[t];
    for (int j = 0; j < MLPH; j++) o = fmaf(hid[j], Wf2[(size_t)j * NCLS + t], o);
    out[(size_t)g * NCLS + t] = o;
  }
}

extern "C" void kernel_launch(void* const* d_in, const int* in_sizes, int n_in,
                              void* d_out, int out_size, void* d_ws, size_t ws_size,
                              hipStream_t stream) {
  const float* x = (const float*)d_in[0];
  const int* ei = (const int*)d_in[1];
  const int* et = (const int*)d_in[2];
  const int* batch = (const int*)d_in[3];
  const float* Wc0 = (const float*)d_in[4];
  const float* bc0 = (const float*)d_in[5];
  const float* Wid0 = (const float*)d_in[6];
  const float* bid0 = (const float*)d_in[7];
  const float* gm0 = (const float*)d_in[8];
  const float* bt0 = (const float*)d_in[9];
  const float* Wc1 = (const float*)d_in[10];
  const float* bc1 = (const float*)d_in[11];
  const float* Wid1 = (const float*)d_in[12];
  const float* bid1 = (const float*)d_in[13];
  const float* gm1 = (const float*)d_in[14];
  const float* bt1 = (const float*)d_in[15];
  const float* Wf1 = (const float*)d_in[16];
  const float* bf1 = (const float*)d_in[17];
  const float* Wf2 = (const float*)d_in[18];
  const float* bf2 = (const float*)d_in[19];
  const int* srcI = ei;
  const int* dstI = ei + NE;
  float* outp = (float*)d_out;

  char* ws = (char*)d_ws;
  size_t off = 0;
  auto take = [&](size_t bytes) -> char* {
    char* p = ws + off;
    off = (off + bytes + 255) & ~(size_t)255;
    return p;
  };
  float* dinv = (float*)take((size_t)NB * 4);
  int* cnt = (int*)take((size_t)NB * 4);
  int* starts = (int*)take((size_t)NB * 4);
  int* bsum = (int*)take((size_t)SCAN_NBLK * 4);
  int* esrc = (int*)take((size_t)NE * 4);
  float* stats1 = (float*)take(2 * C1 * 4);
  float* stats2 = (float*)take(2 * C2 * 4);
  float* sc1 = (float*)take(C1 * 4);
  float* sh1 = (float*)take(C1 * 4);
  float* sc2 = (float*)take(C2 * 4);
  float* sh2 = (float*)take(C2 * 4);
  float* counts = (float*)take((size_t)NG * 4);
  float* pooled = (float*)take((size_t)NG * C2 * 4);
  unsigned short* Wtf1 = (unsigned short*)take((size_t)4 * C0 * C1 * 2);
  unsigned short* Wtf2 = (unsigned short*)take((size_t)4 * C1 * C2 * 2);
  unsigned short* out1 = (unsigned short*)take((size_t)NN * C1 * 2);
  const size_t min_agg = (size_t)3 * 64 * C1 * 2;
  if (off + min_agg > ws_size) {
    k_fill<<<(out_size + 255) / 256, 256, 0, stream>>>(outp, out_size, 100.f);
    return;
  }
  unsigned short* aggXb = (unsigned short*)(ws + off);
  const size_t left = ws_size - off;
  long long ch1 = (long long)(left / ((size_t)3 * C0 * 2)) & ~63LL;
  long long ch2 = (long long)(left / ((size_t)3 * C1 * 2)) & ~63LL;
  if (ch1 > NN) ch1 = NN;
  if (ch2 > NN) ch2 = NN;

  dim3 blk(256);
  hipMemsetAsync(cnt, 0, (size_t)NB * 4, stream);
  hipMemsetAsync(stats1, 0, 2 * C1 * 4, stream);
  hipMemsetAsync(stats2, 0, 2 * C2 * 4, stream);
  hipMemsetAsync(counts, 0, (size_t)NG * 4, stream);
  hipMemsetAsync(pooled, 0, (size_t)NG * C2 * 4, stream);

  // ---- CSR build (histogram doubles as degree) ----
  k_hist<<<(NE + 255) / 256, blk, 0, stream>>>(dstI, et, cnt);
  k_dinvI<<<(NB + 255) / 256, blk, 0, stream>>>(cnt, dinv);
  k_counts<<<(NN + 255) / 256, blk, 0, stream>>>(batch, counts);
  k_scan1<<<SCAN_NBLK, blk, 0, stream>>>(cnt, starts, bsum);
  k_scan2<<<1, 64, 0, stream>>>(bsum);
  k_scan3<<<(NB + 255) / 256, blk, 0, stream>>>(starts, bsum);
  k_place<<<(NE + 255) / 256, blk, 0, stream>>>(srcI, dstI, et, starts, esrc);

  k_prepw<<<(4 * C0 * C1 + 255) / 256, blk, 0, stream>>>(Wid0, Wc0, Wtf1, C0, C1);
  k_prepw<<<(4 * C1 * C2 + 255) / 256, blk, 0, stream>>>(Wid1, Wc1, Wtf2, C1, C2);

  // ---- layer 1: x (f32, 32ch) -> out1 bf16 pre-BN (128ch) + stats1 ----
  for (long long lo = 0; lo < NN; lo += ch1) {
    const int nloc = (int)((NN - lo < ch1) ? (NN - lo) : ch1);
    k_agg<C0, float><<<(3 * nloc * 32 + 255) / 256, blk, 0, stream>>>(starts, esrc, dinv, x, aggXb,
                                                                      (int)lo, nloc);
    k_fin<C0, C1, false, true, false><<<dim3(C1 / 64, nloc / 64), blk, 0, stream>>>(
        x, aggXb, (int)lo, nloc, Wtf1, bid0, bc0, out1, stats1, nullptr, nullptr);
  }
  k_bnfin<<<1, blk, 0, stream>>>(stats1, gm0, bt0, sc1, sh1, C1);
  k_bnfold<<<(int)(((size_t)NN * C1 / 8 + 255) / 256), blk, 0, stream>>>(out1, sc1, sh1);

  // ---- layer 2: out1 bf16 (BN1 folded) -> stats2 + pre-BN pooled ----
  for (long long lo = 0; lo < NN; lo += ch2) {
    const int nloc = (int)((NN - lo < ch2) ? (NN - lo) : ch2);
    k_agg<C1, unsigned short><<<(3 * nloc * 64 + 255) / 256, blk, 0, stream>>>(starts, esrc, dinv, out1,
                                                                               aggXb, (int)lo, nloc);
    k_fin<C1, C2, true, false, true><<<dim3(C2 / 64, nloc / 64), blk, 0, stream>>>(
        out1, aggXb, (int)lo, nloc, Wtf2, bid1, bc1, nullptr, stats2, pooled, batch);
  }
  k_bnfin<<<1, blk, 0, stream>>>(stats2, gm1, bt1, sc2, sh2, C2);

  // ---- MLP head ----
  k_mlp<<<NG, blk, 0, stream>>>(pooled, counts, sc2, sh2, Wf1, bf1, Wf2, bf2, outp);
}